// Round 5
// baseline (973.280 us; speedup 1.0000x reference)
//
#include <hip/hip_runtime.h>

// Problem constants (from reference): N=512, OBS=32, H=128, M=128, L=3
#define NA 512
#define NOBS 32
#define NH 128

typedef const float* fp32p;
typedef __attribute__((ext_vector_type(8))) short bf16x8;
typedef __attribute__((ext_vector_type(4))) float f32x4;

// packed 2xf32 -> 2xbf16 (RNE) in one instruction (gfx950); lo -> bits[15:0]
__device__ __forceinline__ unsigned cvt_pk_bf16(float lo, float hi) {
    unsigned r;
    asm("v_cvt_pk_bf16_f32 %0, %1, %2" : "=v"(r) : "v"(lo), "v"(hi));
    return r;
}

__device__ __forceinline__ bf16x8 wfrag_f4(const float* p) {  // 16B-aligned
    float4 u = *(const float4*)p;
    float4 v = *(const float4*)(p + 4);
    union { unsigned w[4]; bf16x8 f; } r;
    r.w[0] = cvt_pk_bf16(u.x, u.y);
    r.w[1] = cvt_pk_bf16(u.z, u.w);
    r.w[2] = cvt_pk_bf16(v.x, v.y);
    r.w[3] = cvt_pk_bf16(v.z, v.w);
    return r.f;
}

#define HSTR 136   // LDS row stride (shorts), R0/R3-proven padding

// ----------------------------------------- fused encoder + layer-0 ab ------
// grid 512 x 512 (proven): GEMV phases, 4 lanes per output row.
__global__ __launch_bounds__(512) void enc_ab_kernel(
    fp32p obs, fp32p eW1, fp32p eb1, fp32p eW2, fp32p eb2, fp32p eW3, fp32p eb3,
    fp32p mW1, float* __restrict__ z, float* __restrict__ A, float* __restrict__ B) {
    const int i = blockIdx.x;
    const int t = threadIdx.x;
    const int nn = t >> 2;   // output row 0..127
    const int ks = t & 3;    // k-segment

    __shared__ float xs0[NOBS];
    __shared__ float part[4 * NH];
    __shared__ float part2[4 * NH];
    __shared__ float hx[NH], hy[NH], zz[NH];

    if (t < NOBS) xs0[t] = obs[(size_t)i * NOBS + t];
    __syncthreads();
    // L1: K=32 (8 k per lane)
    {
        const float* wr = eW1 + (size_t)nn * NOBS + ks * 8;
        const float4 w0 = *(const float4*)wr;
        const float4 w1 = *(const float4*)(wr + 4);
        const float4 x0 = *(const float4*)&xs0[ks * 8];
        const float4 x1 = *(const float4*)&xs0[ks * 8 + 4];
        part[ks * NH + nn] = w0.x * x0.x + w0.y * x0.y + w0.z * x0.z + w0.w * x0.w +
                             w1.x * x1.x + w1.y * x1.y + w1.z * x1.z + w1.w * x1.w;
    }
    __syncthreads();
    if (t < NH)
        hx[t] = fmaxf(eb1[t] + part[t] + part[NH + t] + part[2 * NH + t] + part[3 * NH + t], 0.f);
    __syncthreads();
    // L2: K=128
    {
        const float* wr = eW2 + (size_t)nn * NH + ks * 4;
        float p = 0.f;
        #pragma unroll
        for (int it = 0; it < 8; ++it) {
            const float4 wv = *(const float4*)(wr + it * 16);
            const float4 xv = *(const float4*)&hx[it * 16 + ks * 4];
            p += wv.x * xv.x + wv.y * xv.y + wv.z * xv.z + wv.w * xv.w;
        }
        part[ks * NH + nn] = p;
    }
    __syncthreads();
    if (t < NH)
        hy[t] = fmaxf(eb2[t] + part[t] + part[NH + t] + part[2 * NH + t] + part[3 * NH + t], 0.f);
    __syncthreads();
    // L3: K=128, no relu -> z
    {
        const float* wr = eW3 + (size_t)nn * NH + ks * 4;
        float p = 0.f;
        #pragma unroll
        for (int it = 0; it < 8; ++it) {
            const float4 wv = *(const float4*)(wr + it * 16);
            const float4 xv = *(const float4*)&hy[it * 16 + ks * 4];
            p += wv.x * xv.x + wv.y * xv.y + wv.z * xv.z + wv.w * xv.w;
        }
        part[ks * NH + nn] = p;
    }
    __syncthreads();
    if (t < NH) {
        const float v = eb3[t] + part[t] + part[NH + t] + part[2 * NH + t] + part[3 * NH + t];
        z[(size_t)i * NH + t] = v;
        zz[t] = v;
    }
    __syncthreads();
    // ab layer 0 (K=128, row stride 257 -> dword loads)
    {
        const float* pr = mW1 + (size_t)nn * 257;
        float pa = 0.f, pb = 0.f;
        #pragma unroll
        for (int it = 0; it < 8; ++it) {
            #pragma unroll
            for (int j = 0; j < 4; ++j) {
                const int k = it * 16 + ks * 4 + j;
                const float x = zz[k];
                pa += x * pr[k];
                pb += x * pr[NH + k];
            }
        }
        part[ks * NH + nn] = pa;
        part2[ks * NH + nn] = pb;
    }
    __syncthreads();
    if (t < NH) {
        A[(size_t)i * NH + t] = part[t] + part[NH + t] + part[2 * NH + t] + part[3 * NH + t];
        B[(size_t)i * NH + t] = part2[t] + part2[NH + t] + part2[2 * NH + t] + part2[3 * NH + t];
    }
}

// -------------------------------------- fused message + update + next-ab ----
// R5: occupancy attack. Counters proved the R3 structure is latency/barrier
// bound (MfmaUtil 14% = exact MFMA roofline share; HBM 1%; LDS-traffic cuts
// in R2/R4 bought nothing). Grid 512 = only 2 blocks/CU resident. So: split
// each agent's j-range across 2 blocks (grid 1024, 256 j's each, 4 x 64-row
// chunks), shrink LDS to ~38 KB (64-row tiles, tail arrays aliased into
// them, distrow[256]) and cap VGPR at 64 via launch_bounds(512,4) -> 4
// blocks/CU, 32 waves/CU (2x latency hiding; R3 needed only 60 VGPRs).
// Cross-half msum reduction: both halves store partials -> __threadfence ->
// atomicAdd on per-agent flag (memset 0 per launch); SECOND arriver acquires,
// sums partials (+511*b3), runs update MLP + next-ab. First arriver exits
// (frees its CU slot). No spinning -> dispatch-order-safe (G16).
__global__ __launch_bounds__(512, 4) void msg_upd_kernel(
    const float* __restrict__ A, const float* __restrict__ B,
    fp32p pos, const float* __restrict__ zin,
    fp32p W1l, fp32p b1, fp32p W2, fp32p b2, fp32p W3, fp32p b3,
    fp32p uW1, fp32p ub1, fp32p uW2, fp32p ub2, fp32p uW3, fp32p ub3,
    fp32p msgW1n, int do_ab,
    float* __restrict__ pm, unsigned* __restrict__ flags,
    float* __restrict__ zout, float* __restrict__ An, float* __restrict__ Bn) {
    const int bid = blockIdx.x;
    const int i = bid >> 1;          // agent
    const int h = bid & 1;           // j-half
    const int jbase = h * 256;
    const int t = threadIdx.x;
    const int lane = t & 63;
    const int w = t >> 6;
    const int q = lane >> 4;
    const int c = lane & 15;
    const int ncol = w * 16 + c;

    __shared__ short h1s[64 * HSTR];   // 17408 B (64-row chunk)
    __shared__ short h2s[64 * HSTR];   // 17408 B
    __shared__ float distrow[256];
    __shared__ float amrow[NH];        // A_i + b1 folded
    __shared__ float wdsr[NH];
    __shared__ float xs2[2 * NH];      // [z_i | msum_i]
    __shared__ unsigned oldp;
    // tail-only arrays aliased into the (then-dead) h1s/h2s tiles
    float* part  = (float*)h1s;            // 4*NH floats
    float* part2 = (float*)h1s + 4 * NH;   // 4*NH floats (4096 B <= 17408)
    float* hx = (float*)h2s;
    float* hy = (float*)h2s + NH;
    float* hz = (float*)h2s + 2 * NH;      // 1536 B <= 17408

    if (t < NH) {
        amrow[t] = A[i * NH + t] + b1[t];
        wdsr[t]  = W1l[t * 257 + 256];
        xs2[t] = zin[(size_t)i * NH + t];
    }
    if (t < 256) {
        const int jg = jbase + t;
        const float2 pi = *(const float2*)&pos[2 * i];
        const float2 pj = *(const float2*)&pos[2 * jg];
        const float dx = pi.x - pj.x, dy = pi.y - pj.y;
        const float s = dx * dx + dy * dy;
        distrow[t] = (jg == i) ? 0.0f : sqrtf(s);
    }

    // register-resident weight fragments (one 16-col n-tile per wave)
    bf16x8 w2f[4], w3f[4];
    {
        const float* w2r = W2 + (size_t)ncol * NH + q * 8;
        const float* w3r = W3 + (size_t)ncol * NH + q * 8;
        #pragma unroll
        for (int kb = 0; kb < 4; ++kb) {
            w2f[kb] = wfrag_f4(w2r + kb * 32);
            w3f[kb] = wfrag_f4(w3r + kb * 32);
        }
    }
    const float b2n = b2[ncol];

    const int m2 = lane * 2;
    float psum = 0.0f;

    for (int c4 = 0; c4 < 4; ++c4) {
        const int j0l = c4 * 64;          // local row base within this half
        const int jg0 = jbase + j0l;      // global j base
        __syncthreads();

        // ---- build h1 chunk (64 x 128) as bf16: 8 rows per wave ----
        {
            const float am0 = amrow[m2],     am1 = amrow[m2 + 1];
            const float wd0 = wdsr[m2],      wd1 = wdsr[m2 + 1];
            #pragma unroll
            for (int rr = 0; rr < 8; ++rr) {
                const int row = rr * 8 + w;
                const int jg  = jg0 + row;
                const float2 bv = *(const float2*)&B[(size_t)jg * NH + m2];
                const float d = distrow[j0l + row];
                const float v0 = fmaxf(fmaf(d, wd0, am0 + bv.x), 0.0f);
                const float v1 = fmaxf(fmaf(d, wd1, am1 + bv.y), 0.0f);
                *(unsigned*)&h1s[row * HSTR + m2] = cvt_pk_bf16(v0, v1);
            }
        }
        __syncthreads();

        // ---- GEMM1: h2 = relu(h1 @ W2^T + b2) ----
        #pragma unroll
        for (int jt = 0; jt < 4; ++jt) {
            f32x4 acc = {0.f, 0.f, 0.f, 0.f};
            const short* arow = &h1s[(jt * 16 + c) * HSTR + q * 8];
            #pragma unroll
            for (int kb = 0; kb < 4; ++kb) {
                bf16x8 a = *(const bf16x8*)(arow + kb * 32);
                acc = __builtin_amdgcn_mfma_f32_16x16x32_bf16(a, w2f[kb], acc, 0, 0, 0);
            }
            const int orow = jt * 16 + q * 4;
            const unsigned p01 = cvt_pk_bf16(fmaxf(acc[0] + b2n, 0.0f),
                                             fmaxf(acc[1] + b2n, 0.0f));
            const unsigned p23 = cvt_pk_bf16(fmaxf(acc[2] + b2n, 0.0f),
                                             fmaxf(acc[3] + b2n, 0.0f));
            h2s[(orow + 0) * HSTR + ncol] = (short)p01;
            h2s[(orow + 1) * HSTR + ncol] = (short)(p01 >> 16);
            h2s[(orow + 2) * HSTR + ncol] = (short)p23;
            h2s[(orow + 3) * HSTR + ncol] = (short)(p23 >> 16);
        }
        __syncthreads();

        // ---- GEMM2: diag-masked column sum of h2 @ W3^T (b3 folded later) ----
        #pragma unroll
        for (int jt = 0; jt < 4; ++jt) {
            f32x4 acc = {0.f, 0.f, 0.f, 0.f};
            const short* arow = &h2s[(jt * 16 + c) * HSTR + q * 8];
            #pragma unroll
            for (int kb = 0; kb < 4; ++kb) {
                bf16x8 a = *(const bf16x8*)(arow + kb * 32);
                acc = __builtin_amdgcn_mfma_f32_16x16x32_bf16(a, w3f[kb], acc, 0, 0, 0);
            }
            #pragma unroll
            for (int r = 0; r < 4; ++r) {
                const int jg = jg0 + jt * 16 + q * 4 + r;
                if (jg != i) psum += acc[r];
            }
        }
    }

    // ---- partial msum: reduce over quads, publish to global ----
    psum += __shfl_xor(psum, 16, 64);
    psum += __shfl_xor(psum, 32, 64);
    if (lane < 16) pm[(size_t)(i * 2 + h) * NH + ncol] = psum;
    __threadfence();                 // release: flush partial stores device-wide
    __syncthreads();                 // all waves fenced before signaling
    if (t == 0) oldp = atomicAdd(&flags[i], 1u);
    __syncthreads();
    if ((oldp & 1u) == 0u) return;   // first arriver: done, free the slot
    __threadfence();                 // acquire: invalidate before reading peer
    if (t < NH)
        xs2[NH + t] = pm[(size_t)(i * 2) * NH + t] + pm[(size_t)(i * 2 + 1) * NH + t]
                      + 511.0f * b3[t];
    __syncthreads();

    // ---- tail: update MLP (fp32 GEMV, 4 lanes per output row) ----
    const int nn = t >> 2;   // output row 0..127
    const int ks = t & 3;    // k-segment
    // L1: K=256
    {
        const float* wr = uW1 + (size_t)nn * 256 + ks * 4;
        float p = 0.f;
        #pragma unroll
        for (int it = 0; it < 16; ++it) {
            const float4 wv = *(const float4*)(wr + it * 16);
            const float4 xv = *(const float4*)&xs2[it * 16 + ks * 4];
            p += wv.x * xv.x + wv.y * xv.y + wv.z * xv.z + wv.w * xv.w;
        }
        part[ks * NH + nn] = p;
    }
    __syncthreads();
    if (t < NH)
        hx[t] = fmaxf(ub1[t] + part[t] + part[NH + t] + part[2 * NH + t] + part[3 * NH + t], 0.f);
    __syncthreads();
    // L2: K=128
    {
        const float* wr = uW2 + (size_t)nn * NH + ks * 4;
        float p = 0.f;
        #pragma unroll
        for (int it = 0; it < 8; ++it) {
            const float4 wv = *(const float4*)(wr + it * 16);
            const float4 xv = *(const float4*)&hx[it * 16 + ks * 4];
            p += wv.x * xv.x + wv.y * xv.y + wv.z * xv.z + wv.w * xv.w;
        }
        part2[ks * NH + nn] = p;
    }
    __syncthreads();
    if (t < NH)
        hy[t] = fmaxf(ub2[t] + part2[t] + part2[NH + t] + part2[2 * NH + t] + part2[3 * NH + t], 0.f);
    __syncthreads();
    // L3: K=128, no relu -> zout + hz
    {
        const float* wr = uW3 + (size_t)nn * NH + ks * 4;
        float p = 0.f;
        #pragma unroll
        for (int it = 0; it < 8; ++it) {
            const float4 wv = *(const float4*)(wr + it * 16);
            const float4 xv = *(const float4*)&hy[it * 16 + ks * 4];
            p += wv.x * xv.x + wv.y * xv.y + wv.z * xv.z + wv.w * xv.w;
        }
        part[ks * NH + nn] = p;
    }
    __syncthreads();
    if (t < NH) {
        const float v = ub3[t] + part[t] + part[NH + t] + part[2 * NH + t] + part[3 * NH + t];
        zout[(size_t)i * NH + t] = v;
        hz[t] = v;
    }
    if (!do_ab) return;
    __syncthreads();
    // ab: A = z@Wi^T, B = z@Wj^T (K=128, row stride 257 -> dword loads)
    {
        const float* pr = msgW1n + (size_t)nn * 257;
        float pa = 0.f, pb = 0.f;
        #pragma unroll
        for (int it = 0; it < 8; ++it) {
            #pragma unroll
            for (int j = 0; j < 4; ++j) {
                const int k = it * 16 + ks * 4 + j;
                const float x = hz[k];
                pa += x * pr[k];
                pb += x * pr[NH + k];
            }
        }
        part[ks * NH + nn] = pa;
        part2[ks * NH + nn] = pb;
    }
    __syncthreads();
    if (t < NH) {
        An[(size_t)i * NH + t] = part[t] + part[NH + t] + part[2 * NH + t] + part[3 * NH + t];
        Bn[(size_t)i * NH + t] = part2[t] + part2[NH + t] + part2[2 * NH + t] + part2[3 * NH + t];
    }
}

// ---------------------------------------------------------------- host ------
extern "C" void kernel_launch(void* const* d_in, const int* in_sizes, int n_in,
                              void* d_out, int out_size, void* d_ws, size_t ws_size,
                              hipStream_t stream) {
    fp32p obs   = (fp32p)d_in[0];
    fp32p pos   = (fp32p)d_in[1];
    fp32p encW1 = (fp32p)d_in[2];  fp32p encb1 = (fp32p)d_in[3];
    fp32p encW2 = (fp32p)d_in[4];  fp32p encb2 = (fp32p)d_in[5];
    fp32p encW3 = (fp32p)d_in[6];  fp32p encb3 = (fp32p)d_in[7];
    fp32p msgW1 = (fp32p)d_in[8];  fp32p msgb1 = (fp32p)d_in[9];
    fp32p msgW2 = (fp32p)d_in[10]; fp32p msgb2 = (fp32p)d_in[11];
    fp32p msgW3 = (fp32p)d_in[12]; fp32p msgb3 = (fp32p)d_in[13];
    fp32p updW1 = (fp32p)d_in[14]; fp32p updb1 = (fp32p)d_in[15];
    fp32p updW2 = (fp32p)d_in[16]; fp32p updb2 = (fp32p)d_in[17];
    fp32p updW3 = (fp32p)d_in[18]; fp32p updb3 = (fp32p)d_in[19];

    // workspace (fp32): zA | zB | A0 | B0 | A1 | B1 | pm | flags  (~2.1 MB)
    float* ws = (float*)d_ws;
    float* zA = ws;
    float* zB = zA + NA * NH;
    float* A0 = zB + NA * NH;
    float* B0 = A0 + NA * NH;
    float* A1 = B0 + NA * NH;
    float* B1 = A1 + NA * NH;
    float* pm = B1 + NA * NH;                 // 512 * 2 * 128 floats
    unsigned* flags = (unsigned*)(pm + (size_t)NA * 2 * NH);

    hipMemsetAsync(flags, 0, NA * sizeof(unsigned), stream);

    enc_ab_kernel<<<NA, 512, 0, stream>>>(obs, encW1, encb1, encW2, encb2,
                                          encW3, encb3, msgW1, zA, A0, B0);

    float* zin = zA;  float* zout = zB;
    float* Ac = A0;   float* Bc = B0;
    float* An = A1;   float* Bn = B1;
    for (int l = 0; l < 3; ++l) {
        const int do_ab = (l < 2);
        float* dst = (l == 2) ? (float*)d_out : zout;
        msg_upd_kernel<<<2 * NA, 512, 0, stream>>>(Ac, Bc, pos, zin,
            msgW1 + (size_t)l * 128 * 257, msgb1 + l * 128,
            msgW2 + (size_t)l * 128 * 128, msgb2 + l * 128,
            msgW3 + (size_t)l * 128 * 128, msgb3 + l * 128,
            updW1 + (size_t)l * 256 * 128, updb1 + l * 128,
            updW2 + (size_t)l * 128 * 128, updb2 + l * 128,
            updW3 + (size_t)l * 128 * 128, updb3 + l * 128,
            msgW1 + (size_t)(l + 1 < 3 ? l + 1 : 0) * 128 * 257, do_ab,
            pm, flags, dst, An, Bn);
        float* tmp;
        tmp = zin; zin = zout; zout = tmp;
        tmp = Ac; Ac = An; An = tmp;
        tmp = Bc; Bc = Bn; Bn = tmp;
    }
}

// Round 6
// 209.618 us; speedup vs baseline: 4.6431x; 4.6431x over previous
//
#include <hip/hip_runtime.h>

// Problem constants (from reference): N=512, OBS=32, H=128, M=128, L=3
#define NA 512
#define NOBS 32
#define NH 128

typedef const float* fp32p;
typedef __attribute__((ext_vector_type(8))) short bf16x8;
typedef __attribute__((ext_vector_type(4))) float f32x4;

// packed 2xf32 -> 2xbf16 (RNE) in one instruction (gfx950); lo -> bits[15:0]
__device__ __forceinline__ unsigned cvt_pk_bf16(float lo, float hi) {
    unsigned r;
    asm("v_cvt_pk_bf16_f32 %0, %1, %2" : "=v"(r) : "v"(lo), "v"(hi));
    return r;
}

__device__ __forceinline__ bf16x8 wfrag_f4(const float* p) {  // 16B-aligned
    float4 u = *(const float4*)p;
    float4 v = *(const float4*)(p + 4);
    union { unsigned w[4]; bf16x8 f; } r;
    r.w[0] = cvt_pk_bf16(u.x, u.y);
    r.w[1] = cvt_pk_bf16(u.z, u.w);
    r.w[2] = cvt_pk_bf16(v.x, v.y);
    r.w[3] = cvt_pk_bf16(v.z, v.w);
    return r.f;
}

#define HSTR 136   // LDS row stride (shorts), R0/R3-proven padding

// ----------------------------------------- fused encoder + layer-0 ab ------
// grid 512 x 512 (proven): GEMV phases, 4 lanes per output row.
__global__ __launch_bounds__(512) void enc_ab_kernel(
    fp32p obs, fp32p eW1, fp32p eb1, fp32p eW2, fp32p eb2, fp32p eW3, fp32p eb3,
    fp32p mW1, float* __restrict__ z, float* __restrict__ A, float* __restrict__ B) {
    const int i = blockIdx.x;
    const int t = threadIdx.x;
    const int nn = t >> 2;   // output row 0..127
    const int ks = t & 3;    // k-segment

    __shared__ float xs0[NOBS];
    __shared__ float part[4 * NH];
    __shared__ float part2[4 * NH];
    __shared__ float hx[NH], hy[NH], zz[NH];

    if (t < NOBS) xs0[t] = obs[(size_t)i * NOBS + t];
    __syncthreads();
    // L1: K=32 (8 k per lane)
    {
        const float* wr = eW1 + (size_t)nn * NOBS + ks * 8;
        const float4 w0 = *(const float4*)wr;
        const float4 w1 = *(const float4*)(wr + 4);
        const float4 x0 = *(const float4*)&xs0[ks * 8];
        const float4 x1 = *(const float4*)&xs0[ks * 8 + 4];
        part[ks * NH + nn] = w0.x * x0.x + w0.y * x0.y + w0.z * x0.z + w0.w * x0.w +
                             w1.x * x1.x + w1.y * x1.y + w1.z * x1.z + w1.w * x1.w;
    }
    __syncthreads();
    if (t < NH)
        hx[t] = fmaxf(eb1[t] + part[t] + part[NH + t] + part[2 * NH + t] + part[3 * NH + t], 0.f);
    __syncthreads();
    // L2: K=128
    {
        const float* wr = eW2 + (size_t)nn * NH + ks * 4;
        float p = 0.f;
        #pragma unroll
        for (int it = 0; it < 8; ++it) {
            const float4 wv = *(const float4*)(wr + it * 16);
            const float4 xv = *(const float4*)&hx[it * 16 + ks * 4];
            p += wv.x * xv.x + wv.y * xv.y + wv.z * xv.z + wv.w * xv.w;
        }
        part[ks * NH + nn] = p;
    }
    __syncthreads();
    if (t < NH)
        hy[t] = fmaxf(eb2[t] + part[t] + part[NH + t] + part[2 * NH + t] + part[3 * NH + t], 0.f);
    __syncthreads();
    // L3: K=128, no relu -> z
    {
        const float* wr = eW3 + (size_t)nn * NH + ks * 4;
        float p = 0.f;
        #pragma unroll
        for (int it = 0; it < 8; ++it) {
            const float4 wv = *(const float4*)(wr + it * 16);
            const float4 xv = *(const float4*)&hy[it * 16 + ks * 4];
            p += wv.x * xv.x + wv.y * xv.y + wv.z * xv.z + wv.w * xv.w;
        }
        part[ks * NH + nn] = p;
    }
    __syncthreads();
    if (t < NH) {
        const float v = eb3[t] + part[t] + part[NH + t] + part[2 * NH + t] + part[3 * NH + t];
        z[(size_t)i * NH + t] = v;
        zz[t] = v;
    }
    __syncthreads();
    // ab layer 0 (K=128, row stride 257 -> dword loads)
    {
        const float* pr = mW1 + (size_t)nn * 257;
        float pa = 0.f, pb = 0.f;
        #pragma unroll
        for (int it = 0; it < 8; ++it) {
            #pragma unroll
            for (int j = 0; j < 4; ++j) {
                const int k = it * 16 + ks * 4 + j;
                const float x = zz[k];
                pa += x * pr[k];
                pb += x * pr[NH + k];
            }
        }
        part[ks * NH + nn] = pa;
        part2[ks * NH + nn] = pb;
    }
    __syncthreads();
    if (t < NH) {
        A[(size_t)i * NH + t] = part[t] + part[NH + t] + part[2 * NH + t] + part[3 * NH + t];
        B[(size_t)i * NH + t] = part2[t] + part2[NH + t] + part2[2 * NH + t] + part2[3 * NH + t];
    }
}

// -------------------------------------- fused message + update + next-ab ----
// R6 = R3 (proven 46.4us) with ONE change: software-pipelined phase order.
// h1s is dead after GEMM1(c4), so BUILD(c4+1) shares the GEMM2(c4) interval
// (global-load latency + VALU hidden under MFMA); GEMM1(c4+1) overwrites h2s
// only after the barrier ending GEMM2(c4). No extra LDS, barrier count in
// the main loop drops 12 -> 8. All phase bodies byte-identical to R3.
// (R5 lesson: cross-block atomic+threadfence reduction costs ~270us of
// device-fence serialization -> never split one agent across blocks.)
__global__ __launch_bounds__(512) void msg_upd_kernel(
    const float* __restrict__ A, const float* __restrict__ B,
    fp32p pos, const float* __restrict__ zin,
    fp32p W1l, fp32p b1, fp32p W2, fp32p b2, fp32p W3, fp32p b3,
    fp32p uW1, fp32p ub1, fp32p uW2, fp32p ub2, fp32p uW3, fp32p ub3,
    fp32p msgW1n, int do_ab,
    float* __restrict__ zout, float* __restrict__ An, float* __restrict__ Bn) {
    const int i = blockIdx.x;
    const int t = threadIdx.x;
    const int lane = t & 63;
    const int w = t >> 6;
    const int q = lane >> 4;
    const int c = lane & 15;
    const int ncol = w * 16 + c;

    __shared__ short h1s[128 * HSTR];  // 34816 B
    __shared__ short h2s[128 * HSTR];  // 34816 B
    __shared__ float distrow[NA];
    __shared__ float amrow[NH];        // A_i + b1 folded
    __shared__ float wdsr[NH];
    __shared__ float xs2[2 * NH];      // [z_i | msum_i]
    __shared__ float part[4 * NH];
    __shared__ float part2[4 * NH];
    __shared__ float hx[NH], hy[NH], hz[NH];

    if (t < NH) {
        amrow[t] = A[i * NH + t] + b1[t];
        wdsr[t]  = W1l[t * 257 + 256];
        xs2[t] = zin[(size_t)i * NH + t];
    }
    {
        const float2 pi = *(const float2*)&pos[2 * i];
        const float2 pj = *(const float2*)&pos[2 * t];
        const float dx = pi.x - pj.x, dy = pi.y - pj.y;
        const float s = dx * dx + dy * dy;
        distrow[t] = (t == i) ? 0.0f : sqrtf(s);
    }

    // register-resident weight fragments (one 16-col n-tile per wave)
    bf16x8 w2f[4], w3f[4];
    {
        const float* w2r = W2 + (size_t)ncol * NH + q * 8;
        const float* w3r = W3 + (size_t)ncol * NH + q * 8;
        #pragma unroll
        for (int kb = 0; kb < 4; ++kb) {
            w2f[kb] = wfrag_f4(w2r + kb * 32);
            w3f[kb] = wfrag_f4(w3r + kb * 32);
        }
    }
    const float b2n = b2[ncol];

    const int m2 = lane * 2;
    float psum = 0.0f;

    __syncthreads();   // amrow/wdsr/distrow ready
    const float am0 = amrow[m2], am1 = amrow[m2 + 1];
    const float wd0 = wdsr[m2],  wd1 = wdsr[m2 + 1];

#define BUILD(c4_) do {                                                      \
        const int j0_ = (c4_) * 128;                                         \
        _Pragma("unroll")                                                    \
        for (int rr = 0; rr < 16; ++rr) {                                    \
            const int row_ = rr * 8 + w;                                     \
            const int jg_ = j0_ + row_;                                      \
            const float2 bv_ = *(const float2*)&B[(size_t)jg_ * NH + m2];    \
            const float d_ = distrow[jg_];                                   \
            const float v0_ = fmaxf(fmaf(d_, wd0, am0 + bv_.x), 0.0f);       \
            const float v1_ = fmaxf(fmaf(d_, wd1, am1 + bv_.y), 0.0f);       \
            *(unsigned*)&h1s[row_ * HSTR + m2] = cvt_pk_bf16(v0_, v1_);      \
        }                                                                    \
    } while (0)

#define GEMM1() do {                                                         \
        _Pragma("unroll")                                                    \
        for (int jt = 0; jt < 8; ++jt) {                                     \
            f32x4 acc = {0.f, 0.f, 0.f, 0.f};                                \
            const short* arow = &h1s[(jt * 16 + c) * HSTR + q * 8];          \
            _Pragma("unroll")                                                \
            for (int kb = 0; kb < 4; ++kb) {                                 \
                bf16x8 a = *(const bf16x8*)(arow + kb * 32);                 \
                acc = __builtin_amdgcn_mfma_f32_16x16x32_bf16(a, w2f[kb], acc, 0, 0, 0); \
            }                                                                \
            const int orow = jt * 16 + q * 4;                                \
            const unsigned p01 = cvt_pk_bf16(fmaxf(acc[0] + b2n, 0.0f),      \
                                             fmaxf(acc[1] + b2n, 0.0f));     \
            const unsigned p23 = cvt_pk_bf16(fmaxf(acc[2] + b2n, 0.0f),      \
                                             fmaxf(acc[3] + b2n, 0.0f));     \
            h2s[(orow + 0) * HSTR + ncol] = (short)p01;                      \
            h2s[(orow + 1) * HSTR + ncol] = (short)(p01 >> 16);              \
            h2s[(orow + 2) * HSTR + ncol] = (short)p23;                      \
            h2s[(orow + 3) * HSTR + ncol] = (short)(p23 >> 16);              \
        }                                                                    \
    } while (0)

#define GEMM2(c4_) do {                                                      \
        const int j0_ = (c4_) * 128;                                         \
        _Pragma("unroll")                                                    \
        for (int jt = 0; jt < 8; ++jt) {                                     \
            f32x4 acc = {0.f, 0.f, 0.f, 0.f};                                \
            const short* arow = &h2s[(jt * 16 + c) * HSTR + q * 8];          \
            _Pragma("unroll")                                                \
            for (int kb = 0; kb < 4; ++kb) {                                 \
                bf16x8 a = *(const bf16x8*)(arow + kb * 32);                 \
                acc = __builtin_amdgcn_mfma_f32_16x16x32_bf16(a, w3f[kb], acc, 0, 0, 0); \
            }                                                                \
            _Pragma("unroll")                                                \
            for (int r = 0; r < 4; ++r) {                                    \
                const int jg_ = j0_ + jt * 16 + q * 4 + r;                   \
                if (jg_ != i) psum += acc[r];                                \
            }                                                                \
        }                                                                    \
    } while (0)

    // pipelined: BUILD(c4+1) overlaps GEMM2(c4); h1s/h2s ping-pong by phase
    BUILD(0);
    __syncthreads();       // h1s(0) ready
    GEMM1();               // h1s(0) -> h2s(0)
    for (int c4 = 0; c4 < 4; ++c4) {
        __syncthreads();   // h2s(c4) ready; h1s free (GEMM1 done)
        if (c4 < 3) {
            BUILD(c4 + 1); // -> h1s (overlaps GEMM2's MFMAs)
            GEMM2(c4);     // h2s -> psum
            __syncthreads();  // h1s(c4+1) ready; h2s fully consumed
            GEMM1();       // h1s(c4+1) -> h2s(c4+1)
        } else {
            GEMM2(c4);
        }
    }
#undef BUILD
#undef GEMM1
#undef GEMM2

    // ---- msum: reduce over quads (same ncol), write straight into xs2 ----
    psum += __shfl_xor(psum, 16, 64);
    psum += __shfl_xor(psum, 32, 64);
    if (lane < 16) xs2[NH + ncol] = psum + 511.0f * b3[ncol];
    __syncthreads();

    // ---- tail: update MLP (fp32 GEMV, 4 lanes per output row) ----
    const int nn = t >> 2;   // output row 0..127
    const int ks = t & 3;    // k-segment
    // L1: K=256
    {
        const float* wr = uW1 + (size_t)nn * 256 + ks * 4;
        float p = 0.f;
        #pragma unroll
        for (int it = 0; it < 16; ++it) {
            const float4 wv = *(const float4*)(wr + it * 16);
            const float4 xv = *(const float4*)&xs2[it * 16 + ks * 4];
            p += wv.x * xv.x + wv.y * xv.y + wv.z * xv.z + wv.w * xv.w;
        }
        part[ks * NH + nn] = p;
    }
    __syncthreads();
    if (t < NH)
        hx[t] = fmaxf(ub1[t] + part[t] + part[NH + t] + part[2 * NH + t] + part[3 * NH + t], 0.f);
    __syncthreads();
    // L2: K=128
    {
        const float* wr = uW2 + (size_t)nn * NH + ks * 4;
        float p = 0.f;
        #pragma unroll
        for (int it = 0; it < 8; ++it) {
            const float4 wv = *(const float4*)(wr + it * 16);
            const float4 xv = *(const float4*)&hx[it * 16 + ks * 4];
            p += wv.x * xv.x + wv.y * xv.y + wv.z * xv.z + wv.w * xv.w;
        }
        part[ks * NH + nn] = p;
    }
    __syncthreads();
    if (t < NH)
        hy[t] = fmaxf(ub2[t] + part[t] + part[NH + t] + part[2 * NH + t] + part[3 * NH + t], 0.f);
    __syncthreads();
    // L3: K=128, no relu -> zout + hz
    {
        const float* wr = uW3 + (size_t)nn * NH + ks * 4;
        float p = 0.f;
        #pragma unroll
        for (int it = 0; it < 8; ++it) {
            const float4 wv = *(const float4*)(wr + it * 16);
            const float4 xv = *(const float4*)&hy[it * 16 + ks * 4];
            p += wv.x * xv.x + wv.y * xv.y + wv.z * xv.z + wv.w * xv.w;
        }
        part[ks * NH + nn] = p;
    }
    __syncthreads();
    if (t < NH) {
        const float v = ub3[t] + part[t] + part[NH + t] + part[2 * NH + t] + part[3 * NH + t];
        zout[(size_t)i * NH + t] = v;
        hz[t] = v;
    }
    if (!do_ab) return;
    __syncthreads();
    // ab: A = z@Wi^T, B = z@Wj^T (K=128, row stride 257 -> dword loads)
    {
        const float* pr = msgW1n + (size_t)nn * 257;
        float pa = 0.f, pb = 0.f;
        #pragma unroll
        for (int it = 0; it < 8; ++it) {
            #pragma unroll
            for (int j = 0; j < 4; ++j) {
                const int k = it * 16 + ks * 4 + j;
                const float x = hz[k];
                pa += x * pr[k];
                pb += x * pr[NH + k];
            }
        }
        part[ks * NH + nn] = pa;
        part2[ks * NH + nn] = pb;
    }
    __syncthreads();
    if (t < NH) {
        An[(size_t)i * NH + t] = part[t] + part[NH + t] + part[2 * NH + t] + part[3 * NH + t];
        Bn[(size_t)i * NH + t] = part2[t] + part2[NH + t] + part2[2 * NH + t] + part2[3 * NH + t];
    }
}

// ---------------------------------------------------------------- host ------
extern "C" void kernel_launch(void* const* d_in, const int* in_sizes, int n_in,
                              void* d_out, int out_size, void* d_ws, size_t ws_size,
                              hipStream_t stream) {
    fp32p obs   = (fp32p)d_in[0];
    fp32p pos   = (fp32p)d_in[1];
    fp32p encW1 = (fp32p)d_in[2];  fp32p encb1 = (fp32p)d_in[3];
    fp32p encW2 = (fp32p)d_in[4];  fp32p encb2 = (fp32p)d_in[5];
    fp32p encW3 = (fp32p)d_in[6];  fp32p encb3 = (fp32p)d_in[7];
    fp32p msgW1 = (fp32p)d_in[8];  fp32p msgb1 = (fp32p)d_in[9];
    fp32p msgW2 = (fp32p)d_in[10]; fp32p msgb2 = (fp32p)d_in[11];
    fp32p msgW3 = (fp32p)d_in[12]; fp32p msgb3 = (fp32p)d_in[13];
    fp32p updW1 = (fp32p)d_in[14]; fp32p updb1 = (fp32p)d_in[15];
    fp32p updW2 = (fp32p)d_in[16]; fp32p updb2 = (fp32p)d_in[17];
    fp32p updW3 = (fp32p)d_in[18]; fp32p updb3 = (fp32p)d_in[19];

    // workspace (fp32): zA | zB | A0 | B0 | A1 | B1  (1.5 MB)
    float* ws = (float*)d_ws;
    float* zA = ws;
    float* zB = zA + NA * NH;
    float* A0 = zB + NA * NH;
    float* B0 = A0 + NA * NH;
    float* A1 = B0 + NA * NH;
    float* B1 = A1 + NA * NH;

    enc_ab_kernel<<<NA, 512, 0, stream>>>(obs, encW1, encb1, encW2, encb2,
                                          encW3, encb3, msgW1, zA, A0, B0);

    float* zin = zA;  float* zout = zB;
    float* Ac = A0;   float* Bc = B0;
    float* An = A1;   float* Bn = B1;
    for (int l = 0; l < 3; ++l) {
        const int do_ab = (l < 2);
        float* dst = (l == 2) ? (float*)d_out : zout;
        msg_upd_kernel<<<NA, 512, 0, stream>>>(Ac, Bc, pos, zin,
            msgW1 + (size_t)l * 128 * 257, msgb1 + l * 128,
            msgW2 + (size_t)l * 128 * 128, msgb2 + l * 128,
            msgW3 + (size_t)l * 128 * 128, msgb3 + l * 128,
            updW1 + (size_t)l * 256 * 128, updb1 + l * 128,
            updW2 + (size_t)l * 128 * 128, updb2 + l * 128,
            updW3 + (size_t)l * 128 * 128, updb3 + l * 128,
            msgW1 + (size_t)(l + 1 < 3 ? l + 1 : 0) * 128 * 257, do_ab,
            dst, An, Bn);
        float* tmp;
        tmp = zin; zin = zout; zout = tmp;
        tmp = Ac; Ac = An; An = tmp;
        tmp = Bc; Bc = Bn; Bn = tmp;
    }
}